// Round 6
// baseline (126.899 us; speedup 1.0000x reference)
//
#include <hip/hip_runtime.h>
#include <hip/hip_bf16.h>

typedef short bf16x8 __attribute__((ext_vector_type(8)));
typedef float f32x4 __attribute__((ext_vector_type(4)));
typedef unsigned short u16x4 __attribute__((ext_vector_type(4)));

#define B_ 16
#define T_ 2048
#define C_ 1024
#define D_ 128
#define M_ (B_ * T_)

static __device__ __forceinline__ unsigned short f2bf(float f) {
    unsigned int u = __builtin_bit_cast(unsigned int, f);
    unsigned int r = (u + 0x7fffu + ((u >> 16) & 1u)) >> 16;
    return (unsigned short)r;
}

// ---------------------------------------------------------------------------
// Kernel 0: W [1024k][128n] fp32 (x3) -> Wt2, a 16n x 8k blocked bf16 layout:
//   Wt2[((nblk*128 + kblk)*128) + (n&15)*8 + (k&7)],  nblk = (o*128+n)>>4.
// One wave-fragment (16 cols x 8 k) is 256B contiguous; a full MFMA B-frag
// read (64 lanes) touches 4 contiguous 256B chunks -> perfectly coalesced.
// ---------------------------------------------------------------------------
#define TPAD 133

__global__ void wt_kernel(const float* __restrict__ Wq, const float* __restrict__ Wk,
                          const float* __restrict__ Wv, unsigned short* __restrict__ Wt2) {
    __shared__ float Tl[64 * TPAD];
    const int o  = blockIdx.x >> 4;    // 0..2
    const int k0 = (blockIdx.x & 15) * 64;
    const float* W = (o == 0) ? Wq : (o == 1) ? Wk : Wv;
    const int tid = threadIdx.x;

    const int kr = tid >> 5;           // 0..7 (+j*8)
    const int n4 = (tid & 31) * 4;
#pragma unroll
    for (int j = 0; j < 8; ++j) {
        float4 v = *(const float4*)(W + (size_t)(k0 + kr + j * 8) * 128 + n4);
        *(float4*)&Tl[(kr + j * 8) * TPAD + n4] = v;
    }
    __syncthreads();

    const int n    = tid & 127;
    const int half = tid >> 7;         // 0..1
#pragma unroll
    for (int j = 0; j < 4; ++j) {
        const int kg = half * 4 + j;   // 0..7 (8 k-granules in this 64-k tile)
        bf16x8 v;
#pragma unroll
        for (int e = 0; e < 8; ++e)
            v[e] = (short)f2bf(Tl[(kg * 8 + e) * TPAD + n]);
        const int nblk = o * 8 + (n >> 4);
        const int kblk = (k0 >> 3) + kg;
        *(bf16x8*)&Wt2[((size_t)nblk * 128 + kblk) * 128 + (n & 15) * 8] = v;
    }
}

// ---------------------------------------------------------------------------
// Kernel 1: fused QKV projection, barrier-free main loop.
//   BM=64 rows of x held in LDS for the FULL K=1024 (128.3 KB). One stage
//   phase + one barrier; then 8 waves free-run: each owns a 64x48 output
//   strip, B-frags global->register (L2-resident Wt2), A-frags from LDS.
//   grid = 512 (M/64), 512 thr.
// ---------------------------------------------------------------------------
#define XSTR 1026   // 1024 + 2 shorts: row stride 513 words -> 2-way read conflicts (free)

__launch_bounds__(512, 1)
__global__ void qkv_kernel(const float* __restrict__ x, const unsigned short* __restrict__ Wt2,
                           unsigned short* __restrict__ Q, unsigned short* __restrict__ K,
                           unsigned short* __restrict__ Vt) {
    __shared__ unsigned short X[64 * XSTR];   // 128.3 KB

    const int tid  = threadIdx.x;
    const int lane = tid & 63;
    const int w    = tid >> 6;   // 0..7: wave owns output cols [w*48, w*48+48)
    const int lr   = lane & 15;
    const int lk   = lane >> 4;  // 0..3
    const int m0   = blockIdx.x * 64;

    // ---- stage: x[m0..m0+63][0..1023] fp32 -> bf16 LDS, coalesced ----
#pragma unroll 8
    for (int j = 0; j < 32; ++j) {
        const int idx = tid + j * 512;      // 0..16383 over 64 rows x 256 f4
        const int row = idx >> 8;
        const int c4  = idx & 255;
        float4 v = *(const float4*)(x + (size_t)(m0 + row) * C_ + c4 * 4);
        u16x4 h;
        h[0] = f2bf(v.x); h[1] = f2bf(v.y); h[2] = f2bf(v.z); h[3] = f2bf(v.w);
        *(u16x4*)&X[row * XSTR + c4 * 4] = h;
    }
    __syncthreads();   // the only barrier

    // ---- main loop: 32 k-steps, no synchronization ----
    f32x4 acc[4][3] = {};
    for (int ko = 0; ko < 32; ++ko) {
        bf16x8 a[4], b[3];
#pragma unroll
        for (int nb = 0; nb < 3; ++nb)
            b[nb] = *(const bf16x8*)(Wt2 + ((size_t)(w * 3 + nb) * 128 + ko * 4 + lk) * 128 + lr * 8);
#pragma unroll
        for (int rb = 0; rb < 4; ++rb)
            a[rb] = *(bf16x8*)&X[(rb * 16 + lr) * XSTR + ko * 32 + lk * 8];
#pragma unroll
        for (int rb = 0; rb < 4; ++rb)
#pragma unroll
            for (int nb = 0; nb < 3; ++nb)
                acc[rb][nb] = __builtin_amdgcn_mfma_f32_16x16x32_bf16(a[rb], b[nb], acc[rb][nb], 0, 0, 0);
    }

    // ---- epilogue. D frag layout: row = lk*4 + r, col = lr ----
    const float qscale = 0.08838834764831845f;  // 128^-0.5 folded into Q
    const int b  = m0 / T_;
    const int t0 = m0 % T_;
#pragma unroll
    for (int rb = 0; rb < 4; ++rb) {
#pragma unroll
        for (int nb = 0; nb < 3; ++nb) {
            const int row0 = rb * 16 + lk * 4;
            const int col  = w * 48 + nb * 16 + lr;
            const int o    = col >> 7;
            const int d    = col & 127;
            f32x4 a = acc[rb][nb];
            if (o == 0) {
#pragma unroll
                for (int r = 0; r < 4; ++r)
                    Q[(size_t)(m0 + row0 + r) * D_ + d] = f2bf(a[r] * qscale);
            } else if (o == 1) {
#pragma unroll
                for (int r = 0; r < 4; ++r)
                    K[(size_t)(m0 + row0 + r) * D_ + d] = f2bf(a[r]);
            } else {
                u16x4 pv;
#pragma unroll
                for (int r = 0; r < 4; ++r) pv[r] = f2bf(a[r]);
                *(u16x4*)&Vt[((size_t)b * D_ + d) * T_ + t0 + row0] = pv;
            }
        }
    }
}

// ---------------------------------------------------------------------------
// Kernel 2: causal flash attention (unchanged — passed R4 & R5).
//   grid = 512: blocks [0,256) q-tiles 0..15, [256,512) q-tiles 31..16.
// ---------------------------------------------------------------------------
#define KSTR 132   // 128 + 4
#define VSTR 68    // 64 + 4
#define PSTR 68

__launch_bounds__(256, 2)
__global__ void attn_kernel(const unsigned short* __restrict__ Q, const unsigned short* __restrict__ K,
                            const unsigned short* __restrict__ Vt, float* __restrict__ out) {
    __shared__ unsigned short Klds[2][64 * KSTR];    // 33.8 KB
    __shared__ unsigned short Vlds[2][128 * VSTR];   // 34.8 KB
    __shared__ unsigned short Plds[4][16 * PSTR];    // 8.7 KB

    const int tid  = threadIdx.x;
    const int lane = tid & 63;
    const int w    = tid >> 6;   // 0..3
    const int lr   = lane & 15;
    const int lk   = lane >> 4;

    int bid = blockIdx.x;
    int batch, qt;
    if (bid < 256) { batch = bid >> 4; qt = bid & 15; }
    else           { bid -= 256; batch = bid >> 4; qt = 31 - (bid & 15); }

    const unsigned short* Qb = Q  + (size_t)batch * T_ * D_;
    const unsigned short* Kb = K  + (size_t)batch * T_ * D_;
    const unsigned short* Vb = Vt + (size_t)batch * D_ * T_;
    float* outb = out + (size_t)batch * T_ * D_;

    const int kxr = tid >> 4;        // 0..15, +j*16
    const int kxc = (tid & 15) * 8;
    const int vxr = tid >> 3;        // 0..31, +j*32
    const int vxc = (tid & 7) * 8;

    bf16x8 kr[4], vr[4];
    auto kv_load = [&](int kvt) {
        const int kv0 = kvt * 64;
#pragma unroll
        for (int j = 0; j < 4; ++j)
            kr[j] = *(const bf16x8*)(Kb + (size_t)(kv0 + kxr + j * 16) * D_ + kxc);
#pragma unroll
        for (int j = 0; j < 4; ++j)
            vr[j] = *(const bf16x8*)(Vb + (size_t)(vxr + j * 32) * T_ + kv0 + vxc);
    };
    auto kv_write = [&](int buf) {
#pragma unroll
        for (int j = 0; j < 4; ++j)
            *(bf16x8*)&Klds[buf][(kxr + j * 16) * KSTR + kxc] = kr[j];
#pragma unroll
        for (int j = 0; j < 4; ++j)
            *(bf16x8*)&Vlds[buf][(vxr + j * 32) * VSTR + vxc] = vr[j];
    };

    const int qw = qt * 64 + w * 16;

    bf16x8 qf[4];
#pragma unroll
    for (int c = 0; c < 4; ++c)
        qf[c] = *(const bf16x8*)(Qb + (size_t)(qw + lr) * D_ + lk * 8 + c * 32);

    f32x4 o_acc[8] = {};
    float mrun[4] = {-1e30f, -1e30f, -1e30f, -1e30f};
    float lrun[4] = {0.f, 0.f, 0.f, 0.f};

    kv_load(0);
    kv_write(0);

    for (int kvt = 0; kvt <= qt; ++kvt) {
        const int cur = kvt & 1;
        __syncthreads();
        if (kvt < qt) kv_load(kvt + 1);

        f32x4 s[4];
#pragma unroll
        for (int nb = 0; nb < 4; ++nb) {
            f32x4 a = {};
#pragma unroll
            for (int c = 0; c < 4; ++c) {
                bf16x8 kf = *(bf16x8*)&Klds[cur][(nb * 16 + lr) * KSTR + lk * 8 + c * 32];
                a = __builtin_amdgcn_mfma_f32_16x16x32_bf16(qf[c], kf, a, 0, 0, 0);
            }
            s[nb] = a;
        }

        if (kvt == qt) {
#pragma unroll
            for (int nb = 0; nb < 4; ++nb)
#pragma unroll
                for (int r = 0; r < 4; ++r) {
                    int qg = qw + lk * 4 + r;
                    int kg = kvt * 64 + nb * 16 + lr;
                    if (kg > qg) s[nb][r] = -1e30f;
                }
        }

        float scale_[4];
#pragma unroll
        for (int r = 0; r < 4; ++r) {
            float mx = fmaxf(fmaxf(s[0][r], s[1][r]), fmaxf(s[2][r], s[3][r]));
            mx = fmaxf(mx, __shfl_xor(mx, 1));
            mx = fmaxf(mx, __shfl_xor(mx, 2));
            mx = fmaxf(mx, __shfl_xor(mx, 4));
            mx = fmaxf(mx, __shfl_xor(mx, 8));
            float mnew = fmaxf(mrun[r], mx);
            scale_[r]  = __expf(mrun[r] - mnew);
            mrun[r]    = mnew;
            lrun[r]   *= scale_[r];
        }
#pragma unroll
        for (int db = 0; db < 8; ++db)
#pragma unroll
            for (int r = 0; r < 4; ++r) o_acc[db][r] *= scale_[r];

#pragma unroll
        for (int nb = 0; nb < 4; ++nb)
#pragma unroll
            for (int r = 0; r < 4; ++r) {
                float p = __expf(s[nb][r] - mrun[r]);
                lrun[r] += p;
                Plds[w][(lk * 4 + r) * PSTR + nb * 16 + lr] = f2bf(p);
            }
        asm volatile("s_waitcnt lgkmcnt(0)" ::: "memory");
        __builtin_amdgcn_sched_barrier(0);

        bf16x8 pa[2];
#pragma unroll
        for (int c = 0; c < 2; ++c)
            pa[c] = *(bf16x8*)&Plds[w][lr * PSTR + lk * 8 + c * 32];
#pragma unroll
        for (int db = 0; db < 8; ++db) {
            f32x4 oo = o_acc[db];
#pragma unroll
            for (int c = 0; c < 2; ++c) {
                bf16x8 vf = *(bf16x8*)&Vlds[cur][(db * 16 + lr) * VSTR + lk * 8 + c * 32];
                oo = __builtin_amdgcn_mfma_f32_16x16x32_bf16(pa[c], vf, oo, 0, 0, 0);
            }
            o_acc[db] = oo;
        }

        if (kvt < qt) kv_write(cur ^ 1);
    }

#pragma unroll
    for (int r = 0; r < 4; ++r) {
        float sgm = lrun[r];
        sgm += __shfl_xor(sgm, 1);
        sgm += __shfl_xor(sgm, 2);
        sgm += __shfl_xor(sgm, 4);
        sgm += __shfl_xor(sgm, 8);
        lrun[r] = 1.0f / sgm;
    }
#pragma unroll
    for (int db = 0; db < 8; ++db)
#pragma unroll
        for (int r = 0; r < 4; ++r)
            outb[(size_t)(qw + lk * 4 + r) * D_ + db * 16 + lr] = o_acc[db][r] * lrun[r];
}

// ---------------------------------------------------------------------------
extern "C" void kernel_launch(void* const* d_in, const int* in_sizes, int n_in,
                              void* d_out, int out_size, void* d_ws, size_t ws_size,
                              hipStream_t stream) {
    const float* x  = (const float*)d_in[0];
    const float* Wq = (const float*)d_in[1];
    const float* Wk = (const float*)d_in[2];
    const float* Wv = (const float*)d_in[3];

    unsigned short* Wt2 = (unsigned short*)d_ws;                          // 768 KB
    unsigned short* Qw  = (unsigned short*)((char*)d_ws + (1 << 20));     // 8 MB
    unsigned short* Kw  = Qw + (size_t)M_ * D_;                           // 8 MB
    unsigned short* Vtw = Kw + (size_t)M_ * D_;                           // 8 MB

    hipLaunchKernelGGL(wt_kernel, dim3(48), dim3(256), 0, stream, Wq, Wk, Wv, Wt2);
    hipLaunchKernelGGL(qkv_kernel, dim3(512), dim3(512), 0, stream, x, Wt2, Qw, Kw, Vtw);
    hipLaunchKernelGGL(attn_kernel, dim3(512), dim3(256), 0, stream, Qw, Kw, Vtw, (float*)d_out);
}

// Round 7
// 118.662 us; speedup vs baseline: 1.0694x; 1.0694x over previous
//
#include <hip/hip_runtime.h>
#include <hip/hip_bf16.h>

typedef short bf16x8 __attribute__((ext_vector_type(8)));
typedef float f32x4 __attribute__((ext_vector_type(4)));
typedef unsigned short u16x4 __attribute__((ext_vector_type(4)));

#define B_ 16
#define T_ 2048
#define C_ 1024
#define D_ 128
#define M_ (B_ * T_)

static __device__ __forceinline__ unsigned short f2bf(float f) {
    unsigned int u = __builtin_bit_cast(unsigned int, f);
    unsigned int r = (u + 0x7fffu + ((u >> 16) & 1u)) >> 16;
    return (unsigned short)r;
}

// async global->LDS, 16B per lane; LDS dest = wave-uniform base + lane*16
static __device__ __forceinline__ void gll16(const unsigned short* g, unsigned short* l) {
    __builtin_amdgcn_global_load_lds(
        (const __attribute__((address_space(1))) void*)g,
        (__attribute__((address_space(3))) void*)l, 16, 0, 0);
}

// ---------------------------------------------------------------------------
// Kernel A: x fp32 -> xb bf16, k-granule swizzle baked:
//   stored granule (g&7)^(row&7) holds logical granule g&7  (granule = 8 elems)
// ---------------------------------------------------------------------------
__global__ void cvt_kernel(const float* __restrict__ x, unsigned short* __restrict__ xb) {
    int idx = blockIdx.x * 256 + threadIdx.x;     // granule id, 4 per thread
#pragma unroll
    for (int it = 0; it < 4; ++it, idx += 1048576) {
        const int row = idx >> 7;
        const int g   = idx & 127;
        const int gs  = (g & ~7) | ((g & 7) ^ (row & 7));
        const float* src = x + (size_t)row * C_ + g * 8;
        float4 v0 = *(const float4*)src;
        float4 v1 = *(const float4*)(src + 4);
        bf16x8 h;
        h[0] = (short)f2bf(v0.x); h[1] = (short)f2bf(v0.y);
        h[2] = (short)f2bf(v0.z); h[3] = (short)f2bf(v0.w);
        h[4] = (short)f2bf(v1.x); h[5] = (short)f2bf(v1.y);
        h[6] = (short)f2bf(v1.z); h[7] = (short)f2bf(v1.w);
        *(bf16x8*)&xb[(size_t)row * C_ + gs * 8] = h;
    }
}

// ---------------------------------------------------------------------------
// Kernel 0: W [1024k][128n] fp32 (x3) -> Wt [384n][1024k] bf16 with the same
// k-granule swizzle baked:  Wt[n][k ^ ((n&7)*8)] = W[k][n].
// ---------------------------------------------------------------------------
#define TPAD 133

__global__ void wt_kernel(const float* __restrict__ Wq, const float* __restrict__ Wk,
                          const float* __restrict__ Wv, unsigned short* __restrict__ Wt) {
    __shared__ float Tl[64 * TPAD];
    const int o  = blockIdx.x >> 4;    // 0..2
    const int k0 = (blockIdx.x & 15) * 64;
    const float* W = (o == 0) ? Wq : (o == 1) ? Wk : Wv;
    const int tid = threadIdx.x;

    const int kr = tid >> 5;           // 0..7 (+j*8)
    const int n4 = (tid & 31) * 4;
#pragma unroll
    for (int j = 0; j < 8; ++j) {
        float4 v = *(const float4*)(W + (size_t)(k0 + kr + j * 8) * 128 + n4);
        *(float4*)&Tl[(kr + j * 8) * TPAD + n4] = v;
    }
    __syncthreads();

    const int nb = tid >> 3;           // 0..31 (+j*32)
    const int kg = (tid & 7) * 8;      // stored-position granule (bytes of 8 shorts)
#pragma unroll
    for (int j = 0; j < 4; ++j) {
        const int nn = nb + j * 32;
        const int kk = kg ^ ((nn & 7) * 8);   // logical k granule
        bf16x8 v;
#pragma unroll
        for (int e = 0; e < 8; ++e)
            v[e] = (short)f2bf(Tl[(kk + e) * TPAD + nn]);
        *(bf16x8*)&Wt[((size_t)o * 128 + nn) * 1024 + k0 + kg] = v;
    }
}

// ---------------------------------------------------------------------------
// Kernel 1: QKV GEMM — m97 replica. BM=BN=128, BK=64, 256 thr / 4 waves (2x2),
// per-wave 64x64 (4x4 frags). Single-buffered 32 KB LDS, gll16 BOTH operands
// (swizzle baked in xb/Wt global layouts, LDS linear, XOR on ds_read).
// grid = 768: nt = bid>>8 selects output (0=Q,1=K,2=Vt), mt = bid&255.
// 3 blocks/CU -> inter-block overlap fills the barrier drain (m114).
// ---------------------------------------------------------------------------
__launch_bounds__(256, 3)
__global__ void qkv_kernel(const unsigned short* __restrict__ xb, const unsigned short* __restrict__ Wt,
                           unsigned short* __restrict__ Q, unsigned short* __restrict__ K,
                           unsigned short* __restrict__ Vt) {
    __shared__ unsigned short Alds[128 * 64];   // 16 KB, linear
    __shared__ unsigned short Blds[128 * 64];   // 16 KB, linear

    const int tid  = threadIdx.x;
    const int lane = tid & 63;
    const int w    = tid >> 6;   // 0..3
    const int wr   = w >> 1;     // 0..1
    const int wc   = w & 1;      // 0..1
    const int lr   = lane & 15;
    const int lk   = lane >> 4;  // 0..3

    const int nt = blockIdx.x >> 8;         // 0..2 (Q/K/V)
    const int mt = blockIdx.x & 255;
    const int m0 = mt * 128;
    const int n0 = nt * 128;

    const int srow = tid >> 3;        // 0..31 (+j*32)
    const int sg   = (tid & 7) * 8;   // granule (shorts), linear copy of swizzled store

    f32x4 acc[4][4] = {};

    for (int t = 0; t < 16; ++t) {
        const int k0 = t * 64;
        // stage: 4 gll rounds for A, 4 for B (each 32 rows x 64 cols bf16)
#pragma unroll
        for (int j = 0; j < 4; ++j) {
            gll16(xb + (size_t)(m0 + j * 32 + srow) * C_ + k0 + sg,
                  &Alds[(j * 32 + w * 8) * 64]);
            gll16(Wt + (size_t)(n0 + j * 32 + srow) * C_ + k0 + sg,
                  &Blds[(j * 32 + w * 8) * 64]);
        }
        __syncthreads();   // drains vmcnt(0): tiles ready

#pragma unroll
        for (int kk = 0; kk < 2; ++kk) {
            bf16x8 a[4], b[4];
#pragma unroll
            for (int rb = 0; rb < 4; ++rb) {
                const int row = wr * 64 + rb * 16 + lr;
                a[rb] = *(bf16x8*)&Alds[row * 64 + ((kk * 32 + lk * 8) ^ ((row & 7) * 8))];
            }
#pragma unroll
            for (int nb = 0; nb < 4; ++nb) {
                const int row = wc * 64 + nb * 16 + lr;
                b[nb] = *(bf16x8*)&Blds[row * 64 + ((kk * 32 + lk * 8) ^ ((row & 7) * 8))];
            }
#pragma unroll
            for (int rb = 0; rb < 4; ++rb)
#pragma unroll
                for (int nb = 0; nb < 4; ++nb)
                    acc[rb][nb] = __builtin_amdgcn_mfma_f32_16x16x32_bf16(a[rb], b[nb], acc[rb][nb], 0, 0, 0);
        }
        __syncthreads();   // LDS free for next tile
    }

    // epilogue. D frag layout: row = lk*4 + r, col = lr
    const float qscale = 0.08838834764831845f;
    const int b  = m0 / T_;
    const int t0 = m0 % T_;
#pragma unroll
    for (int rb = 0; rb < 4; ++rb) {
#pragma unroll
        for (int nb = 0; nb < 4; ++nb) {
            const int row0 = wr * 64 + rb * 16 + lk * 4;
            const int d    = wc * 64 + nb * 16 + lr;
            f32x4 a = acc[rb][nb];
            if (nt == 0) {
#pragma unroll
                for (int r = 0; r < 4; ++r)
                    Q[(size_t)(m0 + row0 + r) * D_ + d] = f2bf(a[r] * qscale);
            } else if (nt == 1) {
#pragma unroll
                for (int r = 0; r < 4; ++r)
                    K[(size_t)(m0 + row0 + r) * D_ + d] = f2bf(a[r]);
            } else {
                u16x4 pv;
#pragma unroll
                for (int r = 0; r < 4; ++r) pv[r] = f2bf(a[r]);
                *(u16x4*)&Vt[((size_t)b * D_ + d) * T_ + t0 + row0] = pv;
            }
        }
    }
}

// ---------------------------------------------------------------------------
// Kernel 2: causal flash attention (unchanged — passed R4/R5/R6).
// ---------------------------------------------------------------------------
#define KSTR 132   // 128 + 4
#define VSTR 68    // 64 + 4
#define PSTR 68

__launch_bounds__(256, 2)
__global__ void attn_kernel(const unsigned short* __restrict__ Q, const unsigned short* __restrict__ K,
                            const unsigned short* __restrict__ Vt, float* __restrict__ out) {
    __shared__ unsigned short Klds[2][64 * KSTR];
    __shared__ unsigned short Vlds[2][128 * VSTR];
    __shared__ unsigned short Plds[4][16 * PSTR];

    const int tid  = threadIdx.x;
    const int lane = tid & 63;
    const int w    = tid >> 6;
    const int lr   = lane & 15;
    const int lk   = lane >> 4;

    int bid = blockIdx.x;
    int batch, qt;
    if (bid < 256) { batch = bid >> 4; qt = bid & 15; }
    else           { bid -= 256; batch = bid >> 4; qt = 31 - (bid & 15); }

    const unsigned short* Qb = Q  + (size_t)batch * T_ * D_;
    const unsigned short* Kb = K  + (size_t)batch * T_ * D_;
    const unsigned short* Vb = Vt + (size_t)batch * D_ * T_;
    float* outb = out + (size_t)batch * T_ * D_;

    const int kxr = tid >> 4;
    const int kxc = (tid & 15) * 8;
    const int vxr = tid >> 3;
    const int vxc = (tid & 7) * 8;

    bf16x8 kr[4], vr[4];
    auto kv_load = [&](int kvt) {
        const int kv0 = kvt * 64;
#pragma unroll
        for (int j = 0; j < 4; ++j)
            kr[j] = *(const bf16x8*)(Kb + (size_t)(kv0 + kxr + j * 16) * D_ + kxc);
#pragma unroll
        for (int j = 0; j < 4; ++j)
            vr[j] = *(const bf16x8*)(Vb + (size_t)(vxr + j * 32) * T_ + kv0 + vxc);
    };
    auto kv_write = [&](int buf) {
#pragma unroll
        for (int j = 0; j < 4; ++j)
            *(bf16x8*)&Klds[buf][(kxr + j * 16) * KSTR + kxc] = kr[j];
#pragma unroll
        for (int j = 0; j < 4; ++j)
            *(bf16x8*)&Vlds[buf][(vxr + j * 32) * VSTR + vxc] = vr[j];
    };

    const int qw = qt * 64 + w * 16;

    bf16x8 qf[4];
#pragma unroll
    for (int c = 0; c < 4; ++c)
        qf[c] = *(const bf16x8*)(Qb + (size_t)(qw + lr) * D_ + lk * 8 + c * 32);

    f32x4 o_acc[8] = {};
    float mrun[4] = {-1e30f, -1e30f, -1e30f, -1e30f};
    float lrun[4] = {0.f, 0.f, 0.f, 0.f};

    kv_load(0);
    kv_write(0);

    for (int kvt = 0; kvt <= qt; ++kvt) {
        const int cur = kvt & 1;
        __syncthreads();
        if (kvt < qt) kv_load(kvt + 1);

        f32x4 s[4];
#pragma unroll
        for (int nb = 0; nb < 4; ++nb) {
            f32x4 a = {};
#pragma unroll
            for (int c = 0; c < 4; ++c) {
                bf16x8 kf = *(bf16x8*)&Klds[cur][(nb * 16 + lr) * KSTR + lk * 8 + c * 32];
                a = __builtin_amdgcn_mfma_f32_16x16x32_bf16(qf[c], kf, a, 0, 0, 0);
            }
            s[nb] = a;
        }

        if (kvt == qt) {
#pragma unroll
            for (int nb = 0; nb < 4; ++nb)
#pragma unroll
                for (int r = 0; r < 4; ++r) {
                    int qg = qw + lk * 4 + r;
                    int kg = kvt * 64 + nb * 16 + lr;
                    if (kg > qg) s[nb][r] = -1e30f;
                }
        }

        float scale_[4];
#pragma unroll
        for (int r = 0; r < 4; ++r) {
            float mx = fmaxf(fmaxf(s[0][r], s[1][r]), fmaxf(s[2][r], s[3][r]));
            mx = fmaxf(mx, __shfl_xor(mx, 1));
            mx = fmaxf(mx, __shfl_xor(mx, 2));
            mx = fmaxf(mx, __shfl_xor(mx, 4));
            mx = fmaxf(mx, __shfl_xor(mx, 8));
            float mnew = fmaxf(mrun[r], mx);
            scale_[r]  = __expf(mrun[r] - mnew);
            mrun[r]    = mnew;
            lrun[r]   *= scale_[r];
        }
#pragma unroll
        for (int db = 0; db < 8; ++db)
#pragma unroll
            for (int r = 0; r < 4; ++r) o_acc[db][r] *= scale_[r];

#pragma unroll
        for (int nb = 0; nb < 4; ++nb)
#pragma unroll
            for (int r = 0; r < 4; ++r) {
                float p = __expf(s[nb][r] - mrun[r]);
                lrun[r] += p;
                Plds[w][(lk * 4 + r) * PSTR + nb * 16 + lr] = f2bf(p);
            }
        asm volatile("s_waitcnt lgkmcnt(0)" ::: "memory");
        __builtin_amdgcn_sched_barrier(0);

        bf16x8 pa[2];
#pragma unroll
        for (int c = 0; c < 2; ++c)
            pa[c] = *(bf16x8*)&Plds[w][lr * PSTR + lk * 8 + c * 32];
#pragma unroll
        for (int db = 0; db < 8; ++db) {
            f32x4 oo = o_acc[db];
#pragma unroll
            for (int c = 0; c < 2; ++c) {
                bf16x8 vf = *(bf16x8*)&Vlds[cur][(db * 16 + lr) * VSTR + lk * 8 + c * 32];
                oo = __builtin_amdgcn_mfma_f32_16x16x32_bf16(pa[c], vf, oo, 0, 0, 0);
            }
            o_acc[db] = oo;
        }

        if (kvt < qt) kv_write(cur ^ 1);
    }

#pragma unroll
    for (int r = 0; r < 4; ++r) {
        float sgm = lrun[r];
        sgm += __shfl_xor(sgm, 1);
        sgm += __shfl_xor(sgm, 2);
        sgm += __shfl_xor(sgm, 4);
        sgm += __shfl_xor(sgm, 8);
        lrun[r] = 1.0f / sgm;
    }
#pragma unroll
    for (int db = 0; db < 8; ++db)
#pragma unroll
        for (int r = 0; r < 4; ++r)
            outb[(size_t)(qw + lk * 4 + r) * D_ + db * 16 + lr] = o_acc[db][r] * lrun[r];
}

// ---------------------------------------------------------------------------
extern "C" void kernel_launch(void* const* d_in, const int* in_sizes, int n_in,
                              void* d_out, int out_size, void* d_ws, size_t ws_size,
                              hipStream_t stream) {
    const float* x  = (const float*)d_in[0];
    const float* Wq = (const float*)d_in[1];
    const float* Wk = (const float*)d_in[2];
    const float* Wv = (const float*)d_in[3];

    unsigned short* xb  = (unsigned short*)d_ws;                            // 64 MB
    unsigned short* Wt  = (unsigned short*)((char*)d_ws + (64u << 20));     // 768 KB
    unsigned short* Qw  = (unsigned short*)((char*)d_ws + (65u << 20));     // 8 MB
    unsigned short* Kw  = Qw + (size_t)M_ * D_;                             // 8 MB
    unsigned short* Vtw = Kw + (size_t)M_ * D_;                             // 8 MB  (total ~89 MB)

    hipLaunchKernelGGL(cvt_kernel, dim3(4096), dim3(256), 0, stream, x, xb);
    hipLaunchKernelGGL(wt_kernel, dim3(48), dim3(256), 0, stream, Wq, Wk, Wv, Wt);
    hipLaunchKernelGGL(qkv_kernel, dim3(768), dim3(256), 0, stream, xb, Wt, Qw, Kw, Vtw);
    hipLaunchKernelGGL(attn_kernel, dim3(512), dim3(256), 0, stream, Qw, Kw, Vtw, (float*)d_out);
}